// Round 4
// baseline (150.087 us; speedup 1.0000x reference)
//
#include <hip/hip_runtime.h>
#include <math.h>

#define NQ 16384
#define MR 16384
#define JTILES (MR / 16)   // 1024

typedef __attribute__((ext_vector_type(8))) short bf16x8;
typedef __attribute__((ext_vector_type(4))) float floatx4;

// round-to-nearest-even fp32 -> bf16 (bit pattern). No NaN/inf in this data.
__device__ __forceinline__ unsigned short bf16_rne(float f) {
    union { float f; unsigned u; } v; v.f = f;
    return (unsigned short)((v.u + 0x7FFFu + ((v.u >> 16) & 1u)) >> 16);
}
__device__ __forceinline__ float bf16_to_f32(unsigned short h) {
    union { unsigned u; float f; } v; v.u = ((unsigned)h) << 16;
    return v.f;
}
// split fp32 v into 3 bf16 terms: v = h + m + l (to ~2^-25 relative)
__device__ __forceinline__ void split3(float v, unsigned short& h,
                                       unsigned short& m, unsigned short& l) {
    h = bf16_rne(v);
    float r1 = v - bf16_to_f32(h);   // exact (Sterbenz)
    m = bf16_rne(r1);
    float r2 = r1 - bf16_to_f32(m);  // exact
    l = bf16_rne(r2);
}

// pack 8 u16 -> one 16B store
__device__ __forceinline__ void store8(unsigned short* p, const unsigned short* s) {
    uint4 a;
    a.x = (unsigned)s[0] | ((unsigned)s[1] << 16);
    a.y = (unsigned)s[2] | ((unsigned)s[3] << 16);
    a.z = (unsigned)s[4] | ((unsigned)s[5] << 16);
    a.w = (unsigned)s[6] | ((unsigned)s[7] << 16);
    *(uint4*)p = a;
}

// Prep refs: split xb into 3 bf16 planes, B-fragment tile order SWIZZLED:
// element (col=j&15, k) of tile j>>4 lives at tile*256 + (k>>3)*128 + col*8 + (k&7).
// Each lane's bf16x8 fragment is a 16B-contiguous run. Unchanged numerics.
__global__ __launch_bounds__(256) void prep_b(const float* __restrict__ xb,
                                              unsigned short* __restrict__ BH,
                                              unsigned short* __restrict__ BM,
                                              unsigned short* __restrict__ BL,
                                              float* __restrict__ xb2) {
    int j = blockIdx.x * 256 + threadIdx.x;
    const float4* r4 = (const float4*)xb + (size_t)j * 4;
    float4 v0 = r4[0], v1 = r4[1], v2 = r4[2], v3 = r4[3];
    float vals[16] = {v0.x, v0.y, v0.z, v0.w, v1.x, v1.y, v1.z, v1.w,
                      v2.x, v2.y, v2.z, v2.w, v3.x, v3.y, v3.z, v3.w};
    float s0 = v0.x * v0.x + v0.y * v0.y + v0.z * v0.z + v0.w * v0.w;
    float s1 = v1.x * v1.x + v1.y * v1.y + v1.z * v1.z + v1.w * v1.w;
    float s2 = v2.x * v2.x + v2.y * v2.y + v2.z * v2.z + v2.w * v2.w;
    float s3 = v3.x * v3.x + v3.y * v3.y + v3.z * v3.z + v3.w * v3.w;
    xb2[j] = (s0 + s1) + (s2 + s3);
    unsigned short h[16], m[16], l[16];
#pragma unroll
    for (int k = 0; k < 16; ++k) split3(vals[k], h[k], m[k], l[k]);
    size_t tb = (size_t)(j >> 4) * 256 + (size_t)(j & 15) * 8;
    store8(BH + tb, h);       store8(BH + tb + 128, h + 8);
    store8(BM + tb, m);       store8(BM + tb + 128, m + 8);
    store8(BL + tb, l);       store8(BL + tb + 128, l + 8);
}

// Main: per wave 4 query-tiles (64 queries); block = 4 waves = 16 q-tiles.
// R1-R3 lessons: occupancy is register-capped at 3 waves/SIMD no matter what;
// every in-structure fix (reg squeeze, more blocks, LDS dbuf) lost. This round
// removes the structure instead: B planes (1.5 MB total) are L2-resident for
// every XCD, so LDS staging + its 2 barriers/chunk bought nothing and forced
// all resident waves into lockstep. Fragments are now read DIRECTLY from
// global (L2-hit), zero LDS, ZERO barriers in the main loop; waves run free
// and the unrolled 8-tile load batch hides L2 latency via the VMEM queue.
// Per-element arithmetic is bitwise identical to the passing kernel:
//   MFMA1: A=[xh|xm] B=[bh|bh]   MFMA2: A=[xh|xm] B=[bm|bm]
//   MFMA3: A=[xh|xl] B=[bl|bh]   (x planes carry the -2), acc init = xb2[col]
// Strict < keeps lowest j on ties.
__global__ __launch_bounds__(256, 3) void nn_mfma(const float* __restrict__ x,
                                                  const unsigned short* __restrict__ BH,
                                                  const unsigned short* __restrict__ BM,
                                                  const unsigned short* __restrict__ BL,
                                                  const float* __restrict__ xb2,
                                                  float* __restrict__ pval,
                                                  int* __restrict__ pidx,
                                                  int msplit) {
    int tid = threadIdx.x;
    int lane = tid & 63;
    int wave = tid >> 6;
    int qt0 = blockIdx.x * 16 + wave * 4;          // 4 q-tiles per wave
    int split = blockIdx.y;
    int JT = JTILES / msplit;                       // tiles in this split
    int t0 = split * JT;

    int n = lane & 15;                              // row (A) / col (B)
    int quad = lane >> 4;
    int halfk = quad & 1;                           // dim half 0..7 / 8..15
    bool low32 = lane < 32;                         // K slot 0..15 vs 16..31
    int eoff2 = halfk * 128 + n * 8;                // shorts, swizzled layout

    // A fragments in-register from raw x (same construction as before)
    bf16x8 A1[4], A3[4];
#pragma unroll
    for (int q = 0; q < 4; ++q) {
        const float* xr = x + ((size_t)(qt0 + q) * 16 + n) * 16 + halfk * 8;
        float4 u0 = ((const float4*)xr)[0];
        float4 u1 = ((const float4*)xr)[1];
        float e[8] = {u0.x, u0.y, u0.z, u0.w, u1.x, u1.y, u1.z, u1.w};
#pragma unroll
        for (int k = 0; k < 8; ++k) {
            unsigned short h, m, l;
            split3(-2.0f * e[k], h, m, l);
            A1[q][k] = (short)(low32 ? h : m);
            A3[q][k] = (short)(low32 ? h : l);
        }
    }

    // Per-lane global fragment pointers; advance 256 shorts (512 B) per tile.
    const unsigned short* pF1 = BH + (size_t)t0 * 256 + eoff2;
    const unsigned short* pF2 = BM + (size_t)t0 * 256 + eoff2;
    const unsigned short* pF3 = (low32 ? BL : BH) + (size_t)t0 * 256 + eoff2;
    const float* pxv = xb2 + t0 * 16 + n;

    float best[4][4];
    int bjt[4][4];
#pragma unroll
    for (int q = 0; q < 4; ++q)
#pragma unroll
        for (int r = 0; r < 4; ++r) { best[q][r] = INFINITY; bjt[q][r] = t0; }

    for (int c = 0; c < JT; c += 8) {
#pragma unroll
        for (int tt = 0; tt < 8; ++tt) {
            int t = c + tt;
            int tg = t0 + t;                        // global j-tile
            bf16x8 f1 = *(const bf16x8*)(pF1 + (size_t)t * 256);
            bf16x8 f2 = *(const bf16x8*)(pF2 + (size_t)t * 256);
            bf16x8 f3 = *(const bf16x8*)(pF3 + (size_t)t * 256);
            float xv = pxv[t * 16];
#pragma unroll
            for (int q = 0; q < 4; ++q) {
                floatx4 acc = {xv, xv, xv, xv};
                acc = __builtin_amdgcn_mfma_f32_16x16x32_bf16(A1[q], f1, acc, 0, 0, 0);
                acc = __builtin_amdgcn_mfma_f32_16x16x32_bf16(A1[q], f2, acc, 0, 0, 0);
                acc = __builtin_amdgcn_mfma_f32_16x16x32_bf16(A3[q], f3, acc, 0, 0, 0);
#pragma unroll
                for (int r = 0; r < 4; ++r) {
                    float s = acc[r];
                    if (s < best[q][r]) { best[q][r] = s; bjt[q][r] = tg; }
                }
            }
        }
    }

    // Cross-lane argmin per row (row = quad*4 + r); lex (value, j).
#pragma unroll
    for (int q = 0; q < 4; ++q) {
#pragma unroll
        for (int r = 0; r < 4; ++r) {
            float v = best[q][r];
            int j = bjt[q][r] * 16 + n;
#pragma unroll
            for (int d = 1; d < 16; d <<= 1) {
                float ov = __shfl_xor(v, d, 64);
                int oj = __shfl_xor(j, d, 64);
                if (ov < v || (ov == v && oj < j)) { v = ov; j = oj; }
            }
            if (n == 0) {
                int gq = (qt0 + q) * 16 + quad * 4 + r;
                pval[(size_t)split * NQ + gq] = v;
                pidx[(size_t)split * NQ + gq] = j;
            }
        }
    }
}

// Combine splits (ascending => lowest j wins ties via strict <), gather y.
__global__ __launch_bounds__(256) void nn_combine(const float* __restrict__ pval,
                                                  const int* __restrict__ pidx,
                                                  const float* __restrict__ y,
                                                  float* __restrict__ out,
                                                  int msplit) {
    int q = blockIdx.x * 256 + threadIdx.x;
    if (q >= NQ) return;
    float bv = INFINITY;
    int bj = 0;
    for (int s = 0; s < msplit; ++s) {
        float v = pval[(size_t)s * NQ + q];
        int id = pidx[(size_t)s * NQ + q];
        if (v < bv) { bv = v; bj = id; }
    }
    out[q] = y[bj];
}

extern "C" void kernel_launch(void* const* d_in, const int* in_sizes, int n_in,
                              void* d_out, int out_size, void* d_ws, size_t ws_size,
                              hipStream_t stream) {
    const float* x  = (const float*)d_in[0];   // [NQ, 16]
    const float* xb = (const float*)d_in[1];   // [MR, 16]
    const float* y  = (const float*)d_in[2];   // [MR]
    float* out = (float*)d_out;                // [NQ]

    // ws need: 3*MR*16*2 (planes) + MR*4 (xb2) + msplit*NQ*8 = 3.58MB @ msplit=16
    int msplit = 16;
    while (msplit > 1 &&
           (size_t)3 * MR * 16 * 2 + (size_t)MR * 4 + (size_t)msplit * NQ * 8 > ws_size) {
        msplit >>= 1;
    }

    unsigned short* BH = (unsigned short*)d_ws;
    unsigned short* BM = BH + (size_t)MR * 16;
    unsigned short* BL = BM + (size_t)MR * 16;
    float* xb2  = (float*)(BL + (size_t)MR * 16);
    float* pval = xb2 + MR;
    int*   pidx = (int*)(pval + (size_t)msplit * NQ);

    prep_b<<<MR / 256, 256, 0, stream>>>(xb, BH, BM, BL, xb2);
    dim3 grid(NQ / 256, msplit);               // 64 x 16 = 1024 blocks
    nn_mfma<<<grid, 256, 0, stream>>>(x, BH, BM, BL, xb2, pval, pidx, msplit);
    nn_combine<<<NQ / 256, 256, 0, stream>>>(pval, pidx, y, out, msplit);
}

// Round 5
// 129.960 us; speedup vs baseline: 1.1549x; 1.1549x over previous
//
#include <hip/hip_runtime.h>
#include <math.h>

#define NQ 16384
#define MR 16384
#define JTILES (MR / 16)   // 1024
#define CHUNK 8            // j-tiles staged per LDS round (12 KB)

typedef __attribute__((ext_vector_type(8))) short bf16x8;
typedef __attribute__((ext_vector_type(4))) float floatx4;

// round-to-nearest-even fp32 -> bf16 (bit pattern). No NaN/inf in this data.
__device__ __forceinline__ unsigned short bf16_rne(float f) {
    union { float f; unsigned u; } v; v.f = f;
    return (unsigned short)((v.u + 0x7FFFu + ((v.u >> 16) & 1u)) >> 16);
}
__device__ __forceinline__ float bf16_to_f32(unsigned short h) {
    union { unsigned u; float f; } v; v.u = ((unsigned)h) << 16;
    return v.f;
}
// split fp32 v into 3 bf16 terms: v = h + m + l (to ~2^-25 relative)
__device__ __forceinline__ void split3(float v, unsigned short& h,
                                       unsigned short& m, unsigned short& l) {
    h = bf16_rne(v);
    float r1 = v - bf16_to_f32(h);   // exact (Sterbenz)
    m = bf16_rne(r1);
    float r2 = r1 - bf16_to_f32(m);  // exact
    l = bf16_rne(r2);
}

// pack 8 u16 -> one 16B store
__device__ __forceinline__ void store8(unsigned short* p, const unsigned short* s) {
    uint4 a;
    a.x = (unsigned)s[0] | ((unsigned)s[1] << 16);
    a.y = (unsigned)s[2] | ((unsigned)s[3] << 16);
    a.z = (unsigned)s[4] | ((unsigned)s[5] << 16);
    a.w = (unsigned)s[6] | ((unsigned)s[7] << 16);
    *(uint4*)p = a;
}

// Prep refs: split xb into 3 bf16 planes, B-fragment tile order SWIZZLED:
// element (col=j&15, k) of tile j>>4 lives at tile*256 + (k>>3)*128 + col*8 + (k&7).
// Unchanged from the passing kernel (numerics + layout identical).
__global__ __launch_bounds__(256) void prep_b(const float* __restrict__ xb,
                                              unsigned short* __restrict__ BH,
                                              unsigned short* __restrict__ BM,
                                              unsigned short* __restrict__ BL,
                                              float* __restrict__ xb2) {
    int j = blockIdx.x * 256 + threadIdx.x;
    const float4* r4 = (const float4*)xb + (size_t)j * 4;
    float4 v0 = r4[0], v1 = r4[1], v2 = r4[2], v3 = r4[3];
    float vals[16] = {v0.x, v0.y, v0.z, v0.w, v1.x, v1.y, v1.z, v1.w,
                      v2.x, v2.y, v2.z, v2.w, v3.x, v3.y, v3.z, v3.w};
    float s0 = v0.x * v0.x + v0.y * v0.y + v0.z * v0.z + v0.w * v0.w;
    float s1 = v1.x * v1.x + v1.y * v1.y + v1.z * v1.z + v1.w * v1.w;
    float s2 = v2.x * v2.x + v2.y * v2.y + v2.z * v2.z + v2.w * v2.w;
    float s3 = v3.x * v3.x + v3.y * v3.y + v3.z * v3.z + v3.w * v3.w;
    xb2[j] = (s0 + s1) + (s2 + s3);
    unsigned short h[16], m[16], l[16];
#pragma unroll
    for (int k = 0; k < 16; ++k) split3(vals[k], h[k], m[k], l[k]);
    size_t tb = (size_t)(j >> 4) * 256 + (size_t)(j & 15) * 8;
    store8(BH + tb, h);       store8(BH + tb + 128, h + 8);
    store8(BM + tb, m);       store8(BM + tb + 128, m + 8);
    store8(BL + tb, l);       store8(BL + tb + 128, l + 8);
}

// Main: per wave 2 query-tiles (32 queries); block = 4 waves = 8 q-tiles (128 q).
// Model from R0-R4 counters: MFMA busy is fixed ~21us, VALU ~35us, dur 72+ =>
// stall-bound at 3 waves/SIMD. True unified V+A allocation of the 4-q wave is
// ~170 regs (occupancy 37% despite VGPR_Count=56). Fix: halve the loop-carried
// state (2 q-tiles: A frags 16 + best/bjt 16) and set __launch_bounds__(256,5)
// -> budget 102 regs, 5 blocks/CU. R1's spill came from the budget-64 (256,8)
// squeeze, not from the 2-q shape itself. LDS staging is kept (block-level
// amortization; a direct-global 2q variant would double L2 traffic to ~the
// 34.5 TB/s ceiling). Barrier lockstep within a block is covered by 5
// independent blocks/CU. Per-element arithmetic bitwise identical:
//   MFMA1: A=[xh|xm] B=[bh|bh]   MFMA2: A=[xh|xm] B=[bm|bm]
//   MFMA3: A=[xh|xl] B=[bl|bh]   (x planes carry the -2), acc init = xb2[col]
// Strict < keeps lowest j on ties.
__global__ __launch_bounds__(256, 5) void nn_mfma(const float* __restrict__ x,
                                                  const unsigned short* __restrict__ BH,
                                                  const unsigned short* __restrict__ BM,
                                                  const unsigned short* __restrict__ BL,
                                                  const float* __restrict__ xb2,
                                                  float* __restrict__ pval,
                                                  int* __restrict__ pidx,
                                                  int msplit) {
    __shared__ unsigned short sB[3][CHUNK * 256];   // 12 KB

    int tid = threadIdx.x;
    int lane = tid & 63;
    int wave = tid >> 6;
    int qt0 = blockIdx.x * 8 + wave * 2;            // 2 q-tiles per wave
    int split = blockIdx.y;
    int JT = JTILES / msplit;                       // tiles in this split
    int t0 = split * JT;

    int n = lane & 15;                              // row (A) / col (B)
    int quad = lane >> 4;
    int halfk = quad & 1;                           // dim half 0..7 / 8..15
    bool low32 = lane < 32;                         // K slot 0..15 vs 16..31
    int eoff2 = halfk * 128 + n * 8;                // shorts, swizzled layout

    // A fragments in-register from raw x (same construction as before)
    bf16x8 A1[2], A3[2];
#pragma unroll
    for (int q = 0; q < 2; ++q) {
        const float* xr = x + ((size_t)(qt0 + q) * 16 + n) * 16 + halfk * 8;
        float4 u0 = ((const float4*)xr)[0];
        float4 u1 = ((const float4*)xr)[1];
        float e[8] = {u0.x, u0.y, u0.z, u0.w, u1.x, u1.y, u1.z, u1.w};
#pragma unroll
        for (int k = 0; k < 8; ++k) {
            unsigned short h, m, l;
            split3(-2.0f * e[k], h, m, l);
            A1[q][k] = (short)(low32 ? h : m);
            A3[q][k] = (short)(low32 ? h : l);
        }
    }

    const unsigned short* f1b = &sB[0][0];
    const unsigned short* f2b = &sB[1][0];
    const unsigned short* f3b = low32 ? &sB[2][0] : &sB[0][0];
    const float* pxv = xb2 + t0 * 16 + n;

    float best[2][4];
    int bjt[2][4];
#pragma unroll
    for (int q = 0; q < 2; ++q)
#pragma unroll
        for (int r = 0; r < 4; ++r) { best[q][r] = INFINITY; bjt[q][r] = t0; }

    for (int c = 0; c < JT; c += CHUNK) {
        __syncthreads();   // previous round's reads complete
        // stage CHUNK tiles x 3 planes: 256 threads x 16B per plane
        {
            size_t gb = (size_t)(t0 + c) * 256 + (size_t)tid * 8;
            uint4 hV = *(const uint4*)(BH + gb);
            uint4 mV = *(const uint4*)(BM + gb);
            uint4 lV = *(const uint4*)(BL + gb);
            ((uint4*)&sB[0][0])[tid] = hV;
            ((uint4*)&sB[1][0])[tid] = mV;
            ((uint4*)&sB[2][0])[tid] = lV;
        }
        __syncthreads();

#pragma unroll
        for (int tt = 0; tt < CHUNK; ++tt) {
            int tg = t0 + c + tt;                   // global j-tile
            bf16x8 f1 = *(const bf16x8*)(f1b + tt * 256 + eoff2);
            bf16x8 f2 = *(const bf16x8*)(f2b + tt * 256 + eoff2);
            bf16x8 f3 = *(const bf16x8*)(f3b + tt * 256 + eoff2);
            float xv = pxv[(c + tt) * 16];
#pragma unroll
            for (int q = 0; q < 2; ++q) {
                floatx4 acc = {xv, xv, xv, xv};
                acc = __builtin_amdgcn_mfma_f32_16x16x32_bf16(A1[q], f1, acc, 0, 0, 0);
                acc = __builtin_amdgcn_mfma_f32_16x16x32_bf16(A1[q], f2, acc, 0, 0, 0);
                acc = __builtin_amdgcn_mfma_f32_16x16x32_bf16(A3[q], f3, acc, 0, 0, 0);
#pragma unroll
                for (int r = 0; r < 4; ++r) {
                    float s = acc[r];
                    if (s < best[q][r]) { best[q][r] = s; bjt[q][r] = tg; }
                }
            }
        }
    }

    // Cross-lane argmin per row (row = quad*4 + r); lex (value, j).
#pragma unroll
    for (int q = 0; q < 2; ++q) {
#pragma unroll
        for (int r = 0; r < 4; ++r) {
            float v = best[q][r];
            int j = bjt[q][r] * 16 + n;
#pragma unroll
            for (int d = 1; d < 16; d <<= 1) {
                float ov = __shfl_xor(v, d, 64);
                int oj = __shfl_xor(j, d, 64);
                if (ov < v || (ov == v && oj < j)) { v = ov; j = oj; }
            }
            if (n == 0) {
                int gq = (qt0 + q) * 16 + quad * 4 + r;
                pval[(size_t)split * NQ + gq] = v;
                pidx[(size_t)split * NQ + gq] = j;
            }
        }
    }
}

// Combine splits (ascending => lowest j wins ties via strict <), gather y.
__global__ __launch_bounds__(256) void nn_combine(const float* __restrict__ pval,
                                                  const int* __restrict__ pidx,
                                                  const float* __restrict__ y,
                                                  float* __restrict__ out,
                                                  int msplit) {
    int q = blockIdx.x * 256 + threadIdx.x;
    if (q >= NQ) return;
    float bv = INFINITY;
    int bj = 0;
    for (int s = 0; s < msplit; ++s) {
        float v = pval[(size_t)s * NQ + q];
        int id = pidx[(size_t)s * NQ + q];
        if (v < bv) { bv = v; bj = id; }
    }
    out[q] = y[bj];
}

extern "C" void kernel_launch(void* const* d_in, const int* in_sizes, int n_in,
                              void* d_out, int out_size, void* d_ws, size_t ws_size,
                              hipStream_t stream) {
    const float* x  = (const float*)d_in[0];   // [NQ, 16]
    const float* xb = (const float*)d_in[1];   // [MR, 16]
    const float* y  = (const float*)d_in[2];   // [MR]
    float* out = (float*)d_out;                // [NQ]

    // ws need: 3*MR*16*2 (planes) + MR*4 (xb2) + msplit*NQ*8 = 3.58MB @ msplit=16
    int msplit = 16;
    while (msplit > 1 &&
           (size_t)3 * MR * 16 * 2 + (size_t)MR * 4 + (size_t)msplit * NQ * 8 > ws_size) {
        msplit >>= 1;
    }

    unsigned short* BH = (unsigned short*)d_ws;
    unsigned short* BM = BH + (size_t)MR * 16;
    unsigned short* BL = BM + (size_t)MR * 16;
    float* xb2  = (float*)(BL + (size_t)MR * 16);
    float* pval = xb2 + MR;
    int*   pidx = (int*)(pval + (size_t)msplit * NQ);

    prep_b<<<MR / 256, 256, 0, stream>>>(xb, BH, BM, BL, xb2);
    dim3 grid(NQ / 128, msplit);               // 128 x 16 = 2048 blocks
    nn_mfma<<<grid, 256, 0, stream>>>(x, BH, BM, BL, xb2, pval, pidx, msplit);
    nn_combine<<<NQ / 256, 256, 0, stream>>>(pval, pidx, y, out, msplit);
}

// Round 6
// 128.869 us; speedup vs baseline: 1.1646x; 1.0085x over previous
//
#include <hip/hip_runtime.h>
#include <math.h>

#define NQ 16384
#define MR 16384
#define JTILES (MR / 16)   // 1024
#define CHUNK 8            // j-tiles staged per LDS round (12 KB)

typedef __attribute__((ext_vector_type(8))) short bf16x8;
typedef __attribute__((ext_vector_type(4))) float floatx4;

// round-to-nearest-even fp32 -> bf16 (bit pattern). No NaN/inf in this data.
__device__ __forceinline__ unsigned short bf16_rne(float f) {
    union { float f; unsigned u; } v; v.f = f;
    return (unsigned short)((v.u + 0x7FFFu + ((v.u >> 16) & 1u)) >> 16);
}
__device__ __forceinline__ float bf16_to_f32(unsigned short h) {
    union { unsigned u; float f; } v; v.u = ((unsigned)h) << 16;
    return v.f;
}
// split fp32 v into 3 bf16 terms: v = h + m + l (to ~2^-25 relative)
__device__ __forceinline__ void split3(float v, unsigned short& h,
                                       unsigned short& m, unsigned short& l) {
    h = bf16_rne(v);
    float r1 = v - bf16_to_f32(h);   // exact (Sterbenz)
    m = bf16_rne(r1);
    float r2 = r1 - bf16_to_f32(m);  // exact
    l = bf16_rne(r2);
}

// pack 8 u16 -> one 16B store
__device__ __forceinline__ void store8(unsigned short* p, const unsigned short* s) {
    uint4 a;
    a.x = (unsigned)s[0] | ((unsigned)s[1] << 16);
    a.y = (unsigned)s[2] | ((unsigned)s[3] << 16);
    a.z = (unsigned)s[4] | ((unsigned)s[5] << 16);
    a.w = (unsigned)s[6] | ((unsigned)s[7] << 16);
    *(uint4*)p = a;
}

// Prep refs: split xb into 3 bf16 planes, B-fragment tile order SWIZZLED:
// element (col=j&15, k) of tile j>>4 lives at tile*256 + (k>>3)*128 + col*8 + (k&7).
// Unchanged from the passing kernel (numerics + layout identical).
__global__ __launch_bounds__(256) void prep_b(const float* __restrict__ xb,
                                              unsigned short* __restrict__ BH,
                                              unsigned short* __restrict__ BM,
                                              unsigned short* __restrict__ BL,
                                              float* __restrict__ xb2) {
    int j = blockIdx.x * 256 + threadIdx.x;
    const float4* r4 = (const float4*)xb + (size_t)j * 4;
    float4 v0 = r4[0], v1 = r4[1], v2 = r4[2], v3 = r4[3];
    float vals[16] = {v0.x, v0.y, v0.z, v0.w, v1.x, v1.y, v1.z, v1.w,
                      v2.x, v2.y, v2.z, v2.w, v3.x, v3.y, v3.z, v3.w};
    float s0 = v0.x * v0.x + v0.y * v0.y + v0.z * v0.z + v0.w * v0.w;
    float s1 = v1.x * v1.x + v1.y * v1.y + v1.z * v1.z + v1.w * v1.w;
    float s2 = v2.x * v2.x + v2.y * v2.y + v2.z * v2.z + v2.w * v2.w;
    float s3 = v3.x * v3.x + v3.y * v3.y + v3.z * v3.z + v3.w * v3.w;
    xb2[j] = (s0 + s1) + (s2 + s3);
    unsigned short h[16], m[16], l[16];
#pragma unroll
    for (int k = 0; k < 16; ++k) split3(vals[k], h[k], m[k], l[k]);
    size_t tb = (size_t)(j >> 4) * 256 + (size_t)(j & 15) * 8;
    store8(BH + tb, h);       store8(BH + tb + 128, h + 8);
    store8(BM + tb, m);       store8(BM + tb + 128, m + 8);
    store8(BL + tb, l);       store8(BL + tb + 128, l + 8);
}

// Main: per wave 2 query-tiles (32 queries); block = 4 waves = 8 q-tiles (128 q).
// Model (R0-R5 counters): MFMA busy fixed ~21us, VALU busy fixed ~38us, and
// dur ~= VALU_work / VALUBusy where VALUBusy scales with resident waves/SIMD.
// R5 proved the 2-q shape fits a 102-reg budget with ZERO spill (VGPR 40,
// WRITE_SIZE flat) and 5 blocks/CU were resident (occ 47% avg incl. the
// 2048/1280 tail round). This round squeezes one more notch: (256,6) ->
// budget 85 regs -> 6 blocks/CU = 75% ceiling (~65% avg with 1.33-round
// tail). LDS 6x12KB=72KB OK. Everything else byte-identical.
//   MFMA1: A=[xh|xm] B=[bh|bh]   MFMA2: A=[xh|xm] B=[bm|bm]
//   MFMA3: A=[xh|xl] B=[bl|bh]   (x planes carry the -2), acc init = xb2[col]
// Strict < keeps lowest j on ties.
__global__ __launch_bounds__(256, 6) void nn_mfma(const float* __restrict__ x,
                                                  const unsigned short* __restrict__ BH,
                                                  const unsigned short* __restrict__ BM,
                                                  const unsigned short* __restrict__ BL,
                                                  const float* __restrict__ xb2,
                                                  float* __restrict__ pval,
                                                  int* __restrict__ pidx,
                                                  int msplit) {
    __shared__ unsigned short sB[3][CHUNK * 256];   // 12 KB

    int tid = threadIdx.x;
    int lane = tid & 63;
    int wave = tid >> 6;
    int qt0 = blockIdx.x * 8 + wave * 2;            // 2 q-tiles per wave
    int split = blockIdx.y;
    int JT = JTILES / msplit;                       // tiles in this split
    int t0 = split * JT;

    int n = lane & 15;                              // row (A) / col (B)
    int quad = lane >> 4;
    int halfk = quad & 1;                           // dim half 0..7 / 8..15
    bool low32 = lane < 32;                         // K slot 0..15 vs 16..31
    int eoff2 = halfk * 128 + n * 8;                // shorts, swizzled layout

    // A fragments in-register from raw x (same construction as before)
    bf16x8 A1[2], A3[2];
#pragma unroll
    for (int q = 0; q < 2; ++q) {
        const float* xr = x + ((size_t)(qt0 + q) * 16 + n) * 16 + halfk * 8;
        float4 u0 = ((const float4*)xr)[0];
        float4 u1 = ((const float4*)xr)[1];
        float e[8] = {u0.x, u0.y, u0.z, u0.w, u1.x, u1.y, u1.z, u1.w};
#pragma unroll
        for (int k = 0; k < 8; ++k) {
            unsigned short h, m, l;
            split3(-2.0f * e[k], h, m, l);
            A1[q][k] = (short)(low32 ? h : m);
            A3[q][k] = (short)(low32 ? h : l);
        }
    }

    const unsigned short* f1b = &sB[0][0];
    const unsigned short* f2b = &sB[1][0];
    const unsigned short* f3b = low32 ? &sB[2][0] : &sB[0][0];
    const float* pxv = xb2 + t0 * 16 + n;

    float best[2][4];
    int bjt[2][4];
#pragma unroll
    for (int q = 0; q < 2; ++q)
#pragma unroll
        for (int r = 0; r < 4; ++r) { best[q][r] = INFINITY; bjt[q][r] = t0; }

    for (int c = 0; c < JT; c += CHUNK) {
        __syncthreads();   // previous round's reads complete
        // stage CHUNK tiles x 3 planes: 256 threads x 16B per plane
        {
            size_t gb = (size_t)(t0 + c) * 256 + (size_t)tid * 8;
            uint4 hV = *(const uint4*)(BH + gb);
            uint4 mV = *(const uint4*)(BM + gb);
            uint4 lV = *(const uint4*)(BL + gb);
            ((uint4*)&sB[0][0])[tid] = hV;
            ((uint4*)&sB[1][0])[tid] = mV;
            ((uint4*)&sB[2][0])[tid] = lV;
        }
        __syncthreads();

#pragma unroll
        for (int tt = 0; tt < CHUNK; ++tt) {
            int tg = t0 + c + tt;                   // global j-tile
            bf16x8 f1 = *(const bf16x8*)(f1b + tt * 256 + eoff2);
            bf16x8 f2 = *(const bf16x8*)(f2b + tt * 256 + eoff2);
            bf16x8 f3 = *(const bf16x8*)(f3b + tt * 256 + eoff2);
            float xv = pxv[(c + tt) * 16];
#pragma unroll
            for (int q = 0; q < 2; ++q) {
                floatx4 acc = {xv, xv, xv, xv};
                acc = __builtin_amdgcn_mfma_f32_16x16x32_bf16(A1[q], f1, acc, 0, 0, 0);
                acc = __builtin_amdgcn_mfma_f32_16x16x32_bf16(A1[q], f2, acc, 0, 0, 0);
                acc = __builtin_amdgcn_mfma_f32_16x16x32_bf16(A3[q], f3, acc, 0, 0, 0);
#pragma unroll
                for (int r = 0; r < 4; ++r) {
                    float s = acc[r];
                    if (s < best[q][r]) { best[q][r] = s; bjt[q][r] = tg; }
                }
            }
        }
    }

    // Cross-lane argmin per row (row = quad*4 + r); lex (value, j).
#pragma unroll
    for (int q = 0; q < 2; ++q) {
#pragma unroll
        for (int r = 0; r < 4; ++r) {
            float v = best[q][r];
            int j = bjt[q][r] * 16 + n;
#pragma unroll
            for (int d = 1; d < 16; d <<= 1) {
                float ov = __shfl_xor(v, d, 64);
                int oj = __shfl_xor(j, d, 64);
                if (ov < v || (ov == v && oj < j)) { v = ov; j = oj; }
            }
            if (n == 0) {
                int gq = (qt0 + q) * 16 + quad * 4 + r;
                pval[(size_t)split * NQ + gq] = v;
                pidx[(size_t)split * NQ + gq] = j;
            }
        }
    }
}

// Combine splits (ascending => lowest j wins ties via strict <), gather y.
__global__ __launch_bounds__(256) void nn_combine(const float* __restrict__ pval,
                                                  const int* __restrict__ pidx,
                                                  const float* __restrict__ y,
                                                  float* __restrict__ out,
                                                  int msplit) {
    int q = blockIdx.x * 256 + threadIdx.x;
    if (q >= NQ) return;
    float bv = INFINITY;
    int bj = 0;
    for (int s = 0; s < msplit; ++s) {
        float v = pval[(size_t)s * NQ + q];
        int id = pidx[(size_t)s * NQ + q];
        if (v < bv) { bv = v; bj = id; }
    }
    out[q] = y[bj];
}

extern "C" void kernel_launch(void* const* d_in, const int* in_sizes, int n_in,
                              void* d_out, int out_size, void* d_ws, size_t ws_size,
                              hipStream_t stream) {
    const float* x  = (const float*)d_in[0];   // [NQ, 16]
    const float* xb = (const float*)d_in[1];   // [MR, 16]
    const float* y  = (const float*)d_in[2];   // [MR]
    float* out = (float*)d_out;                // [NQ]

    // ws need: 3*MR*16*2 (planes) + MR*4 (xb2) + msplit*NQ*8 = 3.58MB @ msplit=16
    int msplit = 16;
    while (msplit > 1 &&
           (size_t)3 * MR * 16 * 2 + (size_t)MR * 4 + (size_t)msplit * NQ * 8 > ws_size) {
        msplit >>= 1;
    }

    unsigned short* BH = (unsigned short*)d_ws;
    unsigned short* BM = BH + (size_t)MR * 16;
    unsigned short* BL = BM + (size_t)MR * 16;
    float* xb2  = (float*)(BL + (size_t)MR * 16);
    float* pval = xb2 + MR;
    int*   pidx = (int*)(pval + (size_t)msplit * NQ);

    prep_b<<<MR / 256, 256, 0, stream>>>(xb, BH, BM, BL, xb2);
    dim3 grid(NQ / 128, msplit);               // 128 x 16 = 2048 blocks
    nn_mfma<<<grid, 256, 0, stream>>>(x, BH, BM, BL, xb2, pval, pidx, msplit);
    nn_combine<<<NQ / 256, 256, 0, stream>>>(pval, pidx, y, out, msplit);
}